// Round 11
// baseline (764.462 us; speedup 1.0000x reference)
//
#include <hip/hip_runtime.h>
#include <hip/hip_cooperative_groups.h>

namespace cg = cooperative_groups;

#define DF 128
#define CHUNK 4096
#define LSTCAP 6144

typedef __bf16 bf16x8 __attribute__((ext_vector_type(8)));
typedef float f32x4 __attribute__((ext_vector_type(4)));

// NOTE: packing assumes n <= 65536, NBUCK <= 256, NCHUNK <= 256.

static __device__ __forceinline__ float lrelu(float x) {
  return x > 0.f ? x : 0.1f * x;
}
static __device__ __forceinline__ unsigned short f2bf(float f) {
  unsigned int u = __float_as_uint(f);
  u += 0x7FFFu + ((u >> 16) & 1u);
  return (unsigned short)(u >> 16);
}
static __device__ __forceinline__ float bf2f(unsigned short h) {
  return __uint_as_float((unsigned int)h << 16);
}

// ---------------------------------------------------------------- W pre-split
__global__ void wsplit_kernel(const float* __restrict__ W1,
                              const float* __restrict__ W2,
                              unsigned short* __restrict__ wfrag) {
  const float* W = (blockIdx.x == 0) ? W1 : W2;
  unsigned short* hi = wfrag + (size_t)blockIdx.x * 32768;
  unsigned short* lo = hi + 16384;
  for (int i = threadIdx.x; i < 16384; i += 256) {
    int k = i >> 7, c = i & 127;
    float w = W[i];
    unsigned short h = f2bf(w);
    unsigned short l = f2bf(w - bf2f(h));
    int fid = (((k >> 5) * 8) + (c >> 4)) * 64 + ((k >> 3) & 3) * 16 + (c & 15);
    int pos = fid * 8 + (k & 7);
    hi[pos] = h;
    lo[pos] = l;
  }
}

// ---------------------------------------------------------------- params
struct MegaP {
  const void* ei;
  const float* x;
  const float* b1;
  const float* b2;
  float* out;
  const unsigned short* wfrag;
  int* M;
  int* btot;
  int* bstart;
  unsigned int* pairs;
  unsigned int* staging;
  int* off;
  int* cnt;
  float* dis;
  unsigned short* srcs;
  unsigned int* srcsu;
  unsigned short* bufG;
  unsigned short* bufH;
  int E, n, NBUCK, NCHUNK;
};

// ---------------------------------------------------------------- gemm tiles
// 32-row tile, 256 threads (4 waves). Split-bf16, 3 MFMA (f32 A), no dis.
static __device__ void gemm_f32_tile(const float* A, const unsigned short* wfrag,
                                     unsigned short* G, int n, int row0,
                                     int tid, unsigned char* smem) {
  unsigned short* Ah = (unsigned short*)smem;   // 4096 ushorts
  unsigned short* Al = Ah + 4096;               // 4096 ushorts
  const float4* A4 = (const float4*)A;
#pragma unroll
  for (int it = 0; it < 4; ++it) {
    int fi = it * 256 + tid;
    int row = fi >> 5, c4 = fi & 31;
    int gr = row0 + row;
    float4 v = make_float4(0.f, 0.f, 0.f, 0.f);
    if (gr < n) v = A4[(size_t)gr * 32 + c4];
    unsigned short h0 = f2bf(v.x), h1 = f2bf(v.y), h2 = f2bf(v.z), h3 = f2bf(v.w);
    unsigned short l0 = f2bf(v.x - bf2f(h0)), l1 = f2bf(v.y - bf2f(h1));
    unsigned short l2 = f2bf(v.z - bf2f(h2)), l3 = f2bf(v.w - bf2f(h3));
    int band = row >> 4, kslab = c4 >> 3;
    int lane = ((c4 >> 1) & 3) * 16 + (row & 15);
    int idx = (((band * 4 + kslab) * 64) + lane) * 8 + (c4 & 1) * 4;
    *(uint2*)&Ah[idx] = make_uint2((unsigned)h0 | ((unsigned)h1 << 16),
                                   (unsigned)h2 | ((unsigned)h3 << 16));
    *(uint2*)&Al[idx] = make_uint2((unsigned)l0 | ((unsigned)l1 << 16),
                                   (unsigned)l2 | ((unsigned)l3 << 16));
  }
  __syncthreads();
  int w = tid >> 6, lane = tid & 63;
  int band = w & 1, ch = w >> 1;
  f32x4 acc[4];
#pragma unroll
  for (int t = 0; t < 4; ++t) acc[t] = (f32x4){0.f, 0.f, 0.f, 0.f};
#pragma unroll
  for (int ks = 0; ks < 4; ++ks) {
    bf16x8 ahi = *(const bf16x8*)&Ah[(((band * 4 + ks) * 64) + lane) * 8];
    bf16x8 alo = *(const bf16x8*)&Al[(((band * 4 + ks) * 64) + lane) * 8];
#pragma unroll
    for (int ct = 0; ct < 4; ++ct) {
      size_t fb = ((size_t)(ks * 8 + ch * 4 + ct) * 64 + lane) * 8;
      bf16x8 whi = *(const bf16x8*)&wfrag[fb];
      bf16x8 wlo = *(const bf16x8*)&wfrag[16384 + fb];
      acc[ct] = __builtin_amdgcn_mfma_f32_16x16x32_bf16(ahi, whi, acc[ct], 0, 0, 0);
      acc[ct] = __builtin_amdgcn_mfma_f32_16x16x32_bf16(ahi, wlo, acc[ct], 0, 0, 0);
      acc[ct] = __builtin_amdgcn_mfma_f32_16x16x32_bf16(alo, whi, acc[ct], 0, 0, 0);
    }
  }
#pragma unroll
  for (int ct = 0; ct < 4; ++ct) {
    int col = ch * 64 + ct * 16 + (lane & 15);
#pragma unroll
    for (int r = 0; r < 4; ++r) {
      int grow = row0 + band * 16 + ((lane >> 4) << 2) + r;
      if (grow < n) G[(size_t)grow * DF + col] = f2bf(acc[ct][r]);
    }
  }
}

// bf16 A, 2 MFMA, folds dis into output.
static __device__ void gemm_bf16_tile(const unsigned short* A,
                                      const unsigned short* wfrag,
                                      const float* dis, unsigned short* G,
                                      int n, int row0, int tid,
                                      unsigned char* smem) {
  unsigned short* Ah = (unsigned short*)smem;   // 4096 ushorts
  float* disS = (float*)(smem + 8192);
  if (tid < 32) {
    int gr = row0 + tid;
    disS[tid] = (gr < n) ? dis[gr] : 0.f;
  }
  const uint4* A4 = (const uint4*)A;
#pragma unroll
  for (int it = 0; it < 2; ++it) {
    int fi = it * 256 + tid;
    int row = fi >> 4, m = fi & 15;
    int gr = row0 + row;
    uint4 v = make_uint4(0u, 0u, 0u, 0u);
    if (gr < n) v = A4[(size_t)gr * 16 + m];
    int band = row >> 4, kslab = m >> 2;
    int lane = (m & 3) * 16 + (row & 15);
    *(uint4*)&Ah[(((band * 4 + kslab) * 64) + lane) * 8] = v;
  }
  __syncthreads();
  int w = tid >> 6, lane = tid & 63;
  int band = w & 1, ch = w >> 1;
  f32x4 acc[4];
#pragma unroll
  for (int t = 0; t < 4; ++t) acc[t] = (f32x4){0.f, 0.f, 0.f, 0.f};
#pragma unroll
  for (int ks = 0; ks < 4; ++ks) {
    bf16x8 ahi = *(const bf16x8*)&Ah[(((band * 4 + ks) * 64) + lane) * 8];
#pragma unroll
    for (int ct = 0; ct < 4; ++ct) {
      size_t fb = ((size_t)(ks * 8 + ch * 4 + ct) * 64 + lane) * 8;
      bf16x8 whi = *(const bf16x8*)&wfrag[fb];
      bf16x8 wlo = *(const bf16x8*)&wfrag[16384 + fb];
      acc[ct] = __builtin_amdgcn_mfma_f32_16x16x32_bf16(ahi, whi, acc[ct], 0, 0, 0);
      acc[ct] = __builtin_amdgcn_mfma_f32_16x16x32_bf16(ahi, wlo, acc[ct], 0, 0, 0);
    }
  }
#pragma unroll
  for (int ct = 0; ct < 4; ++ct) {
    int col = ch * 64 + ct * 16 + (lane & 15);
#pragma unroll
    for (int r = 0; r < 4; ++r) {
      int lrow = band * 16 + ((lane >> 4) << 2) + r;
      int grow = row0 + lrow;
      if (grow < n) G[(size_t)grow * DF + col] = f2bf(acc[ct][r] * disS[lrow]);
    }
  }
}

// ---------------------------------------------------------------- agg nodes
// layer 1: unscaled g, per-edge norm = bf16 dis packed in srcsu high bits.
static __device__ void agg0_node(const unsigned short* g,
                                 const unsigned int* srcsu, const int* off,
                                 const int* cnt, const float* dis,
                                 const float* bias, unsigned short* outH,
                                 int wid, int lane) {
  int slot = lane >> 4, cp = lane & 15;
  float a0 = 0, a1 = 0, a2 = 0, a3 = 0, a4 = 0, a5 = 0, a6 = 0, a7 = 0;
  float dw = dis[wid];
#define AF(U, NR)                                              \
  do {                                                         \
    a0 = fmaf(__uint_as_float((U).x << 16), (NR), a0);         \
    a1 = fmaf(__uint_as_float((U).x & 0xFFFF0000u), (NR), a1); \
    a2 = fmaf(__uint_as_float((U).y << 16), (NR), a2);         \
    a3 = fmaf(__uint_as_float((U).y & 0xFFFF0000u), (NR), a3); \
    a4 = fmaf(__uint_as_float((U).z << 16), (NR), a4);         \
    a5 = fmaf(__uint_as_float((U).z & 0xFFFF0000u), (NR), a5); \
    a6 = fmaf(__uint_as_float((U).w << 16), (NR), a6);         \
    a7 = fmaf(__uint_as_float((U).w & 0xFFFF0000u), (NR), a7); \
  } while (0)
  if (slot == 0) {
    uint4 sv = ((const uint4*)(g + (size_t)wid * DF))[cp];
    AF(sv, dw);
  }
  int s = off[wid], e = s + cnt[wid], jb = s;
  int m8 = s + (((e - s) >> 3) << 3);
  for (; jb < m8; jb += 8) {
    unsigned v0 = srcsu[jb + slot], v1 = srcsu[jb + 4 + slot];
    uint4 u0 = ((const uint4*)(g + (size_t)(v0 & 0xFFFFu) * DF))[cp];
    uint4 u1 = ((const uint4*)(g + (size_t)(v1 & 0xFFFFu) * DF))[cp];
    AF(u0, __uint_as_float(v0 & 0xFFFF0000u));
    AF(u1, __uint_as_float(v1 & 0xFFFF0000u));
  }
  for (; jb + 4 <= e; jb += 4) {
    unsigned v0 = srcsu[jb + slot];
    uint4 u0 = ((const uint4*)(g + (size_t)(v0 & 0xFFFFu) * DF))[cp];
    AF(u0, __uint_as_float(v0 & 0xFFFF0000u));
  }
  int rem = e - jb;
  if (slot < rem) {
    unsigned v0 = srcsu[jb + slot];
    uint4 u0 = ((const uint4*)(g + (size_t)(v0 & 0xFFFFu) * DF))[cp];
    AF(u0, __uint_as_float(v0 & 0xFFFF0000u));
  }
#undef AF
  a0 += __shfl_xor(a0, 16, 64); a1 += __shfl_xor(a1, 16, 64);
  a2 += __shfl_xor(a2, 16, 64); a3 += __shfl_xor(a3, 16, 64);
  a4 += __shfl_xor(a4, 16, 64); a5 += __shfl_xor(a5, 16, 64);
  a6 += __shfl_xor(a6, 16, 64); a7 += __shfl_xor(a7, 16, 64);
  a0 += __shfl_xor(a0, 32, 64); a1 += __shfl_xor(a1, 32, 64);
  a2 += __shfl_xor(a2, 32, 64); a3 += __shfl_xor(a3, 32, 64);
  a4 += __shfl_xor(a4, 32, 64); a5 += __shfl_xor(a5, 32, 64);
  a6 += __shfl_xor(a6, 32, 64); a7 += __shfl_xor(a7, 32, 64);
  if (slot == 0) {
    float4 bA = ((const float4*)bias)[2 * cp];
    float4 bB = ((const float4*)bias)[2 * cp + 1];
    a0 = fmaf(a0, dw, bA.x); a1 = fmaf(a1, dw, bA.y);
    a2 = fmaf(a2, dw, bA.z); a3 = fmaf(a3, dw, bA.w);
    a4 = fmaf(a4, dw, bB.x); a5 = fmaf(a5, dw, bB.y);
    a6 = fmaf(a6, dw, bB.z); a7 = fmaf(a7, dw, bB.w);
    uint4 p;
    p.x = (unsigned)f2bf(a0) | ((unsigned)f2bf(a1) << 16);
    p.y = (unsigned)f2bf(a2) | ((unsigned)f2bf(a3) << 16);
    p.z = (unsigned)f2bf(a4) | ((unsigned)f2bf(a5) << 16);
    p.w = (unsigned)f2bf(a6) | ((unsigned)f2bf(a7) << 16);
    ((uint4*)(outH + (size_t)wid * DF))[cp] = p;
  }
}

// layer 2: pre-scaled g (dis folded in gemm2), plain adds, f32 + lrelu out.
static __device__ void agg1_node(const unsigned short* g,
                                 const unsigned short* srcs, const int* off,
                                 const int* cnt, const float* dis,
                                 const float* bias, float* out, int wid,
                                 int lane) {
  int slot = lane >> 4, cp = lane & 15;
  float a0 = 0, a1 = 0, a2 = 0, a3 = 0, a4 = 0, a5 = 0, a6 = 0, a7 = 0;
#define AA(U)                                       \
  do {                                              \
    a0 += __uint_as_float((U).x << 16);             \
    a1 += __uint_as_float((U).x & 0xFFFF0000u);     \
    a2 += __uint_as_float((U).y << 16);             \
    a3 += __uint_as_float((U).y & 0xFFFF0000u);     \
    a4 += __uint_as_float((U).z << 16);             \
    a5 += __uint_as_float((U).z & 0xFFFF0000u);     \
    a6 += __uint_as_float((U).w << 16);             \
    a7 += __uint_as_float((U).w & 0xFFFF0000u);     \
  } while (0)
  if (slot == 0) {
    uint4 sv = ((const uint4*)(g + (size_t)wid * DF))[cp];
    AA(sv);
  }
  int s = off[wid], e = s + cnt[wid], jb = s;
  int m8 = s + (((e - s) >> 3) << 3);
  for (; jb < m8; jb += 8) {
    int s0 = (int)srcs[jb + slot];
    int s1 = (int)srcs[jb + 4 + slot];
    uint4 u0 = ((const uint4*)(g + (size_t)s0 * DF))[cp];
    uint4 u1 = ((const uint4*)(g + (size_t)s1 * DF))[cp];
    AA(u0);
    AA(u1);
  }
  for (; jb + 4 <= e; jb += 4) {
    int s0 = (int)srcs[jb + slot];
    uint4 u0 = ((const uint4*)(g + (size_t)s0 * DF))[cp];
    AA(u0);
  }
  int rem = e - jb;
  if (slot < rem) {
    int s0 = (int)srcs[jb + slot];
    uint4 u0 = ((const uint4*)(g + (size_t)s0 * DF))[cp];
    AA(u0);
  }
#undef AA
  a0 += __shfl_xor(a0, 16, 64); a1 += __shfl_xor(a1, 16, 64);
  a2 += __shfl_xor(a2, 16, 64); a3 += __shfl_xor(a3, 16, 64);
  a4 += __shfl_xor(a4, 16, 64); a5 += __shfl_xor(a5, 16, 64);
  a6 += __shfl_xor(a6, 16, 64); a7 += __shfl_xor(a7, 16, 64);
  a0 += __shfl_xor(a0, 32, 64); a1 += __shfl_xor(a1, 32, 64);
  a2 += __shfl_xor(a2, 32, 64); a3 += __shfl_xor(a3, 32, 64);
  a4 += __shfl_xor(a4, 32, 64); a5 += __shfl_xor(a5, 32, 64);
  a6 += __shfl_xor(a6, 32, 64); a7 += __shfl_xor(a7, 32, 64);
  if (slot == 0) {
    float dw = dis[wid];
    float4 bA = ((const float4*)bias)[2 * cp];
    float4 bB = ((const float4*)bias)[2 * cp + 1];
    float4 r0, r1;
    r0.x = lrelu(fmaf(a0, dw, bA.x)); r0.y = lrelu(fmaf(a1, dw, bA.y));
    r0.z = lrelu(fmaf(a2, dw, bA.z)); r0.w = lrelu(fmaf(a3, dw, bA.w));
    r1.x = lrelu(fmaf(a4, dw, bB.x)); r1.y = lrelu(fmaf(a5, dw, bB.y));
    r1.z = lrelu(fmaf(a6, dw, bB.z)); r1.w = lrelu(fmaf(a7, dw, bB.w));
    ((float4*)(out + (size_t)wid * DF))[2 * cp] = r0;
    ((float4*)(out + (size_t)wid * DF))[2 * cp + 1] = r1;
  }
}

// ---------------------------------------------------------------- mega kernel
__global__ __launch_bounds__(256, 5) void mega_kernel(MegaP p) {
  cg::grid_group grid = cg::this_grid();
  __shared__ __align__(16) unsigned char smem[28672];
  __shared__ int any32;
  int tid = threadIdx.x;
  int blk = blockIdx.x;
  int nb = gridDim.x;

  // ---- phase A: CSR hist+pack (blocks < NCHUNK) || gemm1 (spare blocks)
  if (blk < p.NCHUNK) {
    int* h = (int*)smem;
    if (tid == 0) any32 = 0;
    h[tid] = 0;
    __syncthreads();
    long long sidx = (long long)tid * (p.E / 256);
    if (sidx < p.E && ((const unsigned int*)p.ei)[2 * sidx + 1] != 0u) any32 = 1;
    __syncthreads();
    int is64 = !any32;
    int base = blk * CHUNK, end = min(base + CHUNK, p.E);
    if (is64) {
      const long long* q = (const long long*)p.ei;
      for (int i = base + tid; i < end; i += 256) {
        int src = (int)q[i];
        int c = (int)q[(size_t)p.E + i];
        atomicAdd(&h[c >> 8], 1);
        p.pairs[i] = ((unsigned)src << 16) | (unsigned)c;
      }
    } else {
      const int* q = (const int*)p.ei;
      for (int i = base + tid; i < end; i += 256) {
        int src = q[i];
        int c = q[(size_t)p.E + i];
        atomicAdd(&h[c >> 8], 1);
        p.pairs[i] = ((unsigned)src << 16) | (unsigned)c;
      }
    }
    __syncthreads();
    if (tid < p.NBUCK) p.M[tid * p.NCHUNK + blk] = h[tid];
  } else {
    int spare = nb - p.NCHUNK;
    int ntile = (p.n + 31) >> 5;
    for (int t = blk - p.NCHUNK; t < ntile; t += spare) {
      __syncthreads();
      gemm_f32_tile(p.x, p.wfrag, p.bufG, p.n, t * 32, tid, smem);
    }
  }
  grid.sync();

  // ---- phase B: matscanA
  if (blk < p.NBUCK) {
    int* s = (int*)smem;
    int v = (tid < p.NCHUNK) ? p.M[blk * p.NCHUNK + tid] : 0;
    s[tid] = v;
    __syncthreads();
    for (int d = 1; d < 256; d <<= 1) {
      int add = (tid >= d) ? s[tid - d] : 0;
      __syncthreads();
      s[tid] += add;
      __syncthreads();
    }
    if (tid < p.NCHUNK) p.M[blk * p.NCHUNK + tid] = s[tid] - v;
    if (tid == 255) p.btot[blk] = s[255];
  }
  grid.sync();

  // ---- phase C: matscanB (block 0)
  if (blk == 0) {
    int* s = (int*)smem;
    int v = (tid < p.NBUCK) ? p.btot[tid] : 0;
    s[tid] = v;
    __syncthreads();
    for (int d = 1; d < 256; d <<= 1) {
      int add = (tid >= d) ? s[tid - d] : 0;
      __syncthreads();
      s[tid] += add;
      __syncthreads();
    }
    if (tid < p.NBUCK) p.bstart[tid] = s[tid] - v;
    if (tid == 0) p.bstart[p.NBUCK] = p.E;
  }
  grid.sync();

  // ---- phase D: rank-scatter into staging
  if (blk < p.NCHUNK) {
    int* rowM = (int*)smem;
    int* lcur = rowM + 256;
    if (tid < p.NBUCK) rowM[tid] = p.M[tid * p.NCHUNK + blk] + p.bstart[tid];
    lcur[tid] = 0;
    __syncthreads();
    int base = blk * CHUNK, end = min(base + CHUNK, p.E);
    for (int i = base + tid; i < end; i += 256) {
      unsigned v = p.pairs[i];
      int b = (int)((v & 0xFFFFu) >> 8);
      int r = atomicAdd(&lcur[b], 1);
      p.staging[rowM[b] + r] = v;
    }
  }
  grid.sync();

  // ---- phase E: per-bucket CSR finalize (off/cnt/dis/srcs)
  if (blk < p.NBUCK) {
    int* h = (int*)smem;
    int* ex = h + 256;
    int* lc = ex + 256;
    unsigned int* lst = (unsigned int*)(lc + 256);
    int base = p.bstart[blk], len = p.bstart[blk + 1] - base;
    h[tid] = 0;
    lc[tid] = 0;
    __syncthreads();
    for (int i = tid; i < len; i += 256) {
      unsigned v = p.staging[base + i];
      if (i < LSTCAP) lst[i] = v;
      atomicAdd(&h[v & 255u], 1);
    }
    __syncthreads();
    int my = h[tid];
    ex[tid] = my;
    __syncthreads();
    for (int d = 1; d < 256; d <<= 1) {
      int add = (tid >= d) ? ex[tid - d] : 0;
      __syncthreads();
      ex[tid] += add;
      __syncthreads();
    }
    int excl = ex[tid] - my;
    ex[tid] = excl;
    int node = (blk << 8) + tid;
    if (node < p.n) {
      p.off[node] = base + excl;
      p.cnt[node] = my;
      p.dis[node] = rsqrtf((float)(my + 1));
    }
    __syncthreads();
    for (int i = tid; i < len; i += 256) {
      unsigned v = (i < LSTCAP) ? lst[i] : p.staging[base + i];
      int ci = (int)(v & 255u);
      int r = atomicAdd(&lc[ci], 1);
      p.srcs[base + ex[ci] + r] = (unsigned short)(v >> 16);
    }
  }
  grid.sync();

  // ---- phase F: annotate srcsu = (bf16(dis[src]) << 16) | src
  for (int i = blk * 256 + tid; i < p.E; i += nb * 256) {
    int s = (int)p.srcs[i];
    p.srcsu[i] = ((unsigned)f2bf(p.dis[s]) << 16) | (unsigned)s;
  }
  grid.sync();

  // ---- phase G: agg layer 1 (bufG unscaled + srcsu) -> bufH bf16
  {
    int wv = tid >> 6, lane = tid & 63;
    for (int bw = blk * 4; bw < p.n; bw += nb * 4) {
      int wid = bw + wv;
      if (wid < p.n)
        agg0_node(p.bufG, p.srcsu, p.off, p.cnt, p.dis, p.b1, p.bufH, wid, lane);
    }
  }
  grid.sync();

  // ---- phase H: gemm2 (bufH @ W2, fold dis) -> bufG
  {
    int ntile = (p.n + 31) >> 5;
    for (int t = blk; t < ntile; t += nb) {
      __syncthreads();
      gemm_bf16_tile(p.bufH, p.wfrag + 32768, p.dis, p.bufG, p.n, t * 32, tid,
                     smem);
    }
  }
  grid.sync();

  // ---- phase I: agg layer 2 -> out (f32, lrelu)
  {
    int wv = tid >> 6, lane = tid & 63;
    for (int bw = blk * 4; bw < p.n; bw += nb * 4) {
      int wid = bw + wv;
      if (wid < p.n)
        agg1_node(p.bufG, p.srcs, p.off, p.cnt, p.dis, p.b2, p.out, wid, lane);
    }
  }
}

// ---------------------------------------------------------------- launch
extern "C" void kernel_launch(void* const* d_in, const int* in_sizes, int n_in,
                              void* d_out, int out_size, void* d_ws, size_t ws_size,
                              hipStream_t stream) {
  const float* x  = (const float*)d_in[0];
  const void*  ei = d_in[1];
  const float* W1 = (const float*)d_in[2];
  const float* b1 = (const float*)d_in[3];
  const float* W2 = (const float*)d_in[4];
  const float* b2 = (const float*)d_in[5];
  float* out = (float*)d_out;

  int n = in_sizes[0] / DF;  // 50000
  int E = in_sizes[1] / 2;   // 800000
  int NBUCK = (n + 255) >> 8;            // 196
  int NCHUNK = (E + CHUNK - 1) / CHUNK;  // 196

  char* w = (char*)d_ws;
  auto carve = [&](size_t bytes) {
    char* p = w;
    w += (bytes + 15) & ~(size_t)15;
    return p;
  };
  float* dis    = (float*)carve((size_t)n * 4);
  int*   cnt    = (int*)carve((size_t)n * 4);
  int*   off    = (int*)carve((size_t)n * 4);
  int*   bstart = (int*)carve((size_t)(NBUCK + 1) * 4);
  int*   btot   = (int*)carve((size_t)NBUCK * 4);
  int*   M      = (int*)carve((size_t)NCHUNK * NBUCK * 4);
  unsigned short* wfrag = (unsigned short*)carve(131072);  // 2 layers x (hi+lo)
  unsigned int* pairs   = (unsigned int*)carve((size_t)E * 4);
  unsigned int* staging = (unsigned int*)carve((size_t)E * 4);
  unsigned short* srcs  = (unsigned short*)carve((size_t)E * 2);
  unsigned int* srcsu   = (unsigned int*)carve((size_t)E * 4);
  unsigned short* bufG  = (unsigned short*)carve((size_t)n * DF * 2);
  unsigned short* bufH  = (unsigned short*)carve((size_t)n * DF * 2);

  wsplit_kernel<<<2, 256, 0, stream>>>(W1, W2, wfrag);

  MegaP P;
  P.ei = ei; P.x = x; P.b1 = b1; P.b2 = b2; P.out = out;
  P.wfrag = wfrag; P.M = M; P.btot = btot; P.bstart = bstart;
  P.pairs = pairs; P.staging = staging;
  P.off = off; P.cnt = cnt; P.dis = dis;
  P.srcs = srcs; P.srcsu = srcsu;
  P.bufG = bufG; P.bufH = bufH;
  P.E = E; P.n = n; P.NBUCK = NBUCK; P.NCHUNK = NCHUNK;

  int occ = 0;
  hipOccupancyMaxActiveBlocksPerMultiprocessor(&occ, mega_kernel, 256, 0);
  if (occ < 1) occ = 1;
  long long nbL = (long long)occ * 256;  // 256 CUs on MI355X
  int nb = (int)(nbL > 2048 ? 2048 : nbL);
  if (nb < NCHUNK + 64) nb = NCHUNK + 64;  // ensure spare blocks for gemm1

  void* args[] = {(void*)&P};
  hipLaunchCooperativeKernel((const void*)mega_kernel, dim3(nb), dim3(256),
                             args, 0, stream);
}

// Round 12
// 166.014 us; speedup vs baseline: 4.6048x; 4.6048x over previous
//
#include <hip/hip_runtime.h>

#define DF 128      // feature dim
#define CHUNK 2048  // edges per chunk in counting sort
#define LSTCAP 6144 // LDS staging cap in p2 (bucket avg ~4096 + slack)

typedef __bf16 bf16x8 __attribute__((ext_vector_type(8)));
typedef float f32x4 __attribute__((ext_vector_type(4)));

// NOTE: packing assumes n <= 65536, NBUCK <= 256, NCHUNK <= 512
// (problem fixes n = 50000, E = 800000 -> NBUCK = 196, NCHUNK = 391).

// ---------------------------------------------------------------- utilities
static __device__ __forceinline__ float lrelu(float x) {
  return x > 0.f ? x : 0.1f * x;
}
static __device__ __forceinline__ unsigned short f2bf(float f) {
  unsigned int u = __float_as_uint(f);
  u += 0x7FFFu + ((u >> 16) & 1u);
  return (unsigned short)(u >> 16);
}
static __device__ __forceinline__ float bf2f(unsigned short h) {
  return __uint_as_float((unsigned int)h << 16);
}

// ---------------------------------------------------------------- prep:
// blocks 0,1: split W1/W2 into bf16 hi/lo in MFMA B-fragment-linear order.
// block 2: detect int64 vs int32 edge_index.
__global__ void prep_kernel(const float* __restrict__ W1,
                            const float* __restrict__ W2,
                            unsigned short* __restrict__ wfrag,
                            const unsigned int* __restrict__ ei_u, int E,
                            int* __restrict__ flag) {
  if (blockIdx.x == 2) {
    __shared__ int any32;
    if (threadIdx.x == 0) any32 = 0;
    __syncthreads();
    long long idx = (long long)threadIdx.x * (E / 256);
    if (idx < E) {
      if (ei_u[2 * idx + 1] != 0u) any32 = 1;
    }
    __syncthreads();
    if (threadIdx.x == 0) flag[0] = any32 ? 0 : 1;  // 1 => int64
    return;
  }
  const float* W = (blockIdx.x == 0) ? W1 : W2;
  unsigned short* hi = wfrag + (size_t)blockIdx.x * 32768;
  unsigned short* lo = hi + 16384;
  for (int i = threadIdx.x; i < 16384; i += 256) {
    int k = i >> 7, c = i & 127;
    float w = W[i];
    unsigned short h = f2bf(w);
    unsigned short l = f2bf(w - bf2f(h));
    int fid = (((k >> 5) * 8) + (c >> 4)) * 64 + ((k >> 3) & 3) * 16 + (c & 15);
    int pos = fid * 8 + (k & 7);
    hi[pos] = h;
    lo[pos] = l;
  }
}

// ---------------------------------------------------------------- pass 1a:
// per-chunk bucket histogram (bucket = target >> 8) + pack pairs.
// M stored TRANSPOSED: M[bucket * NCHUNK + chunk].
__global__ __launch_bounds__(256) void p1a_kernel(
    const void* __restrict__ ei, int E, const int* __restrict__ flag,
    int* __restrict__ M, unsigned int* __restrict__ pairs, int NBUCK,
    int NCHUNK) {
  __shared__ int h[256];
  int tid = threadIdx.x;
  h[tid] = 0;
  __syncthreads();
  int is64 = flag[0];
  int base = blockIdx.x * CHUNK;
  int end = min(base + CHUNK, E);
  if (is64) {
    const long long* p = (const long long*)ei;
    for (int i = base + tid; i < end; i += 256) {
      int src = (int)p[i];
      int c = (int)p[(size_t)E + i];
      atomicAdd(&h[c >> 8], 1);
      pairs[i] = ((unsigned)src << 16) | (unsigned)c;
    }
  } else {
    const int* p = (const int*)ei;
    for (int i = base + tid; i < end; i += 256) {
      int src = p[i];
      int c = p[(size_t)E + i];
      atomicAdd(&h[c >> 8], 1);
      pairs[i] = ((unsigned)src << 16) | (unsigned)c;
    }
  }
  __syncthreads();
  if (tid < NBUCK) M[tid * NCHUNK + blockIdx.x] = h[tid];
}

// ---------------------------------------------------------------- matscanA:
// one block per bucket: exclusive scan of that bucket's chunk row (T=2 per
// thread), write row total into btot.
__global__ __launch_bounds__(256) void matscanA_kernel(int* __restrict__ M,
                                                       int* __restrict__ btot,
                                                       int NCHUNK) {
  __shared__ int s[256];
  int tid = threadIdx.x;
  int base = blockIdx.x * NCHUNK;
  int i0 = tid * 2, i1 = tid * 2 + 1;
  int v0 = (i0 < NCHUNK) ? M[base + i0] : 0;
  int v1 = (i1 < NCHUNK) ? M[base + i1] : 0;
  int loc = v0 + v1;
  s[tid] = loc;
  __syncthreads();
  for (int d = 1; d < 256; d <<= 1) {
    int add = (tid >= d) ? s[tid - d] : 0;
    __syncthreads();
    s[tid] += add;
    __syncthreads();
  }
  int excl = s[tid] - loc;
  if (i0 < NCHUNK) M[base + i0] = excl;
  if (i1 < NCHUNK) M[base + i1] = excl + v0;
  if (tid == 255) btot[blockIdx.x] = s[255];
}

// ---------------------------------------------------------------- pass 1c:
// scatter pairs into exact per-(chunk,bucket) staging slots. bstart computed
// in-block by scanning btot (196 values). Ranks via LDS atomics.
__global__ __launch_bounds__(256) void p1c_kernel(
    const unsigned int* __restrict__ pairs, int E, const int* __restrict__ M,
    const int* __restrict__ btot, int NBUCK, int NCHUNK,
    unsigned int* __restrict__ staging) {
  __shared__ int bs[256];
  __shared__ int rowM[256];
  __shared__ int lcur[256];
  int tid = threadIdx.x;
  int blk = blockIdx.x;
  int v = (tid < NBUCK) ? btot[tid] : 0;
  bs[tid] = v;
  __syncthreads();
  for (int d = 1; d < 256; d <<= 1) {
    int add = (tid >= d) ? bs[tid - d] : 0;
    __syncthreads();
    bs[tid] += add;
    __syncthreads();
  }
  if (tid < NBUCK) rowM[tid] = M[tid * NCHUNK + blk] + (bs[tid] - v);
  lcur[tid] = 0;
  __syncthreads();
  int base = blk * CHUNK;
  int end = min(base + CHUNK, E);
  for (int i = base + tid; i < end; i += 256) {
    unsigned pv = pairs[i];
    int b = (int)((pv & 0xFFFFu) >> 8);
    int r = atomicAdd(&lcur[b], 1);
    staging[rowM[b] + r] = pv;
  }
}

// ---------------------------------------------------------------- pass 2:
// one block per bucket: LDS histogram + scan of the 256 nodes, emit
// off/cnt/dis densely, scatter srcs (ushort) into the bucket's CSR window.
__global__ __launch_bounds__(256) void p2_kernel(
    const unsigned int* __restrict__ staging, const int* __restrict__ btot,
    int NBUCK, int* __restrict__ off, int* __restrict__ cnt,
    float* __restrict__ dis, unsigned short* __restrict__ srcs, int n) {
  __shared__ int bs[256], h[256], ex[256], lcur[256];
  __shared__ unsigned int lst[LSTCAP];
  int tid = threadIdx.x;
  int b = blockIdx.x;
  int v = (tid < NBUCK) ? btot[tid] : 0;
  bs[tid] = v;
  h[tid] = 0;
  lcur[tid] = 0;
  __syncthreads();
  for (int d = 1; d < 256; d <<= 1) {
    int add = (tid >= d) ? bs[tid - d] : 0;
    __syncthreads();
    bs[tid] += add;
    __syncthreads();
  }
  int lenb = btot[b];
  int base = bs[b] - lenb;  // exclusive prefix at b
  __syncthreads();
  for (int i = tid; i < lenb; i += 256) {
    unsigned int pv = staging[base + i];
    if (i < LSTCAP) lst[i] = pv;
    atomicAdd(&h[pv & 255u], 1);
  }
  __syncthreads();
  int my = h[tid];
  ex[tid] = my;
  __syncthreads();
  for (int d = 1; d < 256; d <<= 1) {
    int add = (tid >= d) ? ex[tid - d] : 0;
    __syncthreads();
    ex[tid] += add;
    __syncthreads();
  }
  int excl = ex[tid] - my;
  ex[tid] = excl;
  int node = (b << 8) + tid;
  if (node < n) {
    off[node] = base + excl;
    cnt[node] = my;
    dis[node] = rsqrtf((float)(my + 1));  // deg incl self loop >= 1
  }
  __syncthreads();
  for (int i = tid; i < lenb; i += 256) {
    unsigned int pv = (i < LSTCAP) ? lst[i] : staging[base + i];
    int ci = (int)(pv & 255u);
    int r = atomicAdd(&lcur[ci], 1);
    srcs[base + ex[ci] + r] = (unsigned short)(pv >> 16);
  }
}

// ---------------------------------------------------------------- MFMA GEMM, fp32 A (split hi/lo, 3 MFMA)
// G_bf16[n x 128] = dis[row] * (A_f32[n x 128] @ W[128 x 128])
// Epilogue: stage C tile in LDS (stride 136), store coalesced uint4.
__global__ __launch_bounds__(256, 8) void gemm_f32_kernel(
    const float* __restrict__ A, const unsigned short* __restrict__ wfrag,
    const float* __restrict__ dis, unsigned short* __restrict__ G, int n) {
  __shared__ unsigned short Ah[2][4][64][8];
  __shared__ unsigned short Al[2][4][64][8];
  __shared__ unsigned short Cs[32 * 136];
  __shared__ float disS[32];
  int tid = threadIdx.x;
  int row0 = blockIdx.x * 32;

  if (tid < 32) {
    int gr = row0 + tid;
    disS[tid] = (gr < n) ? dis[gr] : 0.f;
  }

  const float4* A4 = (const float4*)A;
#pragma unroll
  for (int it = 0; it < 4; ++it) {
    int fi = it * 256 + tid;
    int row = fi >> 5;          // 0..31
    int c4 = fi & 31;           // float4 index along k
    int gr = row0 + row;
    float4 v = make_float4(0.f, 0.f, 0.f, 0.f);
    if (gr < n) v = A4[(size_t)gr * 32 + c4];
    unsigned short h0 = f2bf(v.x), h1 = f2bf(v.y), h2 = f2bf(v.z), h3 = f2bf(v.w);
    unsigned short l0 = f2bf(v.x - bf2f(h0)), l1 = f2bf(v.y - bf2f(h1));
    unsigned short l2 = f2bf(v.z - bf2f(h2)), l3 = f2bf(v.w - bf2f(h3));
    int band = row >> 4;
    int kslab = c4 >> 3;
    int lane = ((c4 >> 1) & 3) * 16 + (row & 15);
    int e0 = (c4 & 1) * 4;
    *(uint2*)&Ah[band][kslab][lane][e0] =
        make_uint2((unsigned int)h0 | ((unsigned int)h1 << 16),
                   (unsigned int)h2 | ((unsigned int)h3 << 16));
    *(uint2*)&Al[band][kslab][lane][e0] =
        make_uint2((unsigned int)l0 | ((unsigned int)l1 << 16),
                   (unsigned int)l2 | ((unsigned int)l3 << 16));
  }
  __syncthreads();

  int w = tid >> 6, lane = tid & 63;
  int band = w & 1, ch = w >> 1;

  f32x4 acc[4];
#pragma unroll
  for (int t = 0; t < 4; ++t) acc[t] = (f32x4){0.f, 0.f, 0.f, 0.f};

#pragma unroll
  for (int ks = 0; ks < 4; ++ks) {
    bf16x8 ahi = *(const bf16x8*)&Ah[band][ks][lane][0];
    bf16x8 alo = *(const bf16x8*)&Al[band][ks][lane][0];
#pragma unroll
    for (int ct = 0; ct < 4; ++ct) {
      size_t fb = ((size_t)(ks * 8 + ch * 4 + ct) * 64 + lane) * 8;
      bf16x8 whi = *(const bf16x8*)&wfrag[fb];
      bf16x8 wlo = *(const bf16x8*)&wfrag[16384 + fb];
      acc[ct] = __builtin_amdgcn_mfma_f32_16x16x32_bf16(ahi, whi, acc[ct], 0, 0, 0);
      acc[ct] = __builtin_amdgcn_mfma_f32_16x16x32_bf16(ahi, wlo, acc[ct], 0, 0, 0);
      acc[ct] = __builtin_amdgcn_mfma_f32_16x16x32_bf16(alo, whi, acc[ct], 0, 0, 0);
    }
  }

#pragma unroll
  for (int ct = 0; ct < 4; ++ct) {
    int col = ch * 64 + ct * 16 + (lane & 15);
#pragma unroll
    for (int r = 0; r < 4; ++r) {
      int lrow = band * 16 + ((lane >> 4) << 2) + r;
      Cs[lrow * 136 + col] = f2bf(acc[ct][r] * disS[lrow]);
    }
  }
  __syncthreads();
#pragma unroll
  for (int it = 0; it < 2; ++it) {
    int fi = it * 256 + tid;   // 0..511 = 32 rows x 16 uint4
    int row = fi >> 4, q = fi & 15;
    int gr = row0 + row;
    if (gr < n)
      ((uint4*)(G + (size_t)gr * DF))[q] = *(uint4*)&Cs[row * 136 + q * 8];
  }
}

// ---------------------------------------------------------------- MFMA GEMM, bf16 A (2 MFMA)
__global__ __launch_bounds__(256, 8) void gemm_bf16_kernel(
    const unsigned short* __restrict__ A, const unsigned short* __restrict__ wfrag,
    const float* __restrict__ dis, unsigned short* __restrict__ G, int n) {
  __shared__ unsigned short Ah[2][4][64][8];
  __shared__ unsigned short Cs[32 * 136];
  __shared__ float disS[32];
  int tid = threadIdx.x;
  int row0 = blockIdx.x * 32;

  if (tid < 32) {
    int gr = row0 + tid;
    disS[tid] = (gr < n) ? dis[gr] : 0.f;
  }

  const uint4* A4 = (const uint4*)A;  // 8 bf16 per uint4
#pragma unroll
  for (int it = 0; it < 2; ++it) {
    int fi = it * 256 + tid;    // 0..511
    int row = fi >> 4;          // 0..31
    int m = fi & 15;            // 8-k group
    int gr = row0 + row;
    uint4 v = make_uint4(0u, 0u, 0u, 0u);
    if (gr < n) v = A4[(size_t)gr * 16 + m];
    int band = row >> 4;
    int kslab = m >> 2;
    int lane = (m & 3) * 16 + (row & 15);
    *(uint4*)&Ah[band][kslab][lane][0] = v;
  }
  __syncthreads();

  int w = tid >> 6, lane = tid & 63;
  int band = w & 1, ch = w >> 1;

  f32x4 acc[4];
#pragma unroll
  for (int t = 0; t < 4; ++t) acc[t] = (f32x4){0.f, 0.f, 0.f, 0.f};

#pragma unroll
  for (int ks = 0; ks < 4; ++ks) {
    bf16x8 ahi = *(const bf16x8*)&Ah[band][ks][lane][0];
#pragma unroll
    for (int ct = 0; ct < 4; ++ct) {
      size_t fb = ((size_t)(ks * 8 + ch * 4 + ct) * 64 + lane) * 8;
      bf16x8 whi = *(const bf16x8*)&wfrag[fb];
      bf16x8 wlo = *(const bf16x8*)&wfrag[16384 + fb];
      acc[ct] = __builtin_amdgcn_mfma_f32_16x16x32_bf16(ahi, whi, acc[ct], 0, 0, 0);
      acc[ct] = __builtin_amdgcn_mfma_f32_16x16x32_bf16(ahi, wlo, acc[ct], 0, 0, 0);
    }
  }

#pragma unroll
  for (int ct = 0; ct < 4; ++ct) {
    int col = ch * 64 + ct * 16 + (lane & 15);
#pragma unroll
    for (int r = 0; r < 4; ++r) {
      int lrow = band * 16 + ((lane >> 4) << 2) + r;
      Cs[lrow * 136 + col] = f2bf(acc[ct][r] * disS[lrow]);
    }
  }
  __syncthreads();
#pragma unroll
  for (int it = 0; it < 2; ++it) {
    int fi = it * 256 + tid;
    int row = fi >> 4, q = fi & 15;
    int gr = row0 + row;
    if (gr < n)
      ((uint4*)(G + (size_t)gr * DF))[q] = *(uint4*)&Cs[row * 136 + q * 8];
  }
}

// ---------------------------------------------------------------- aggregation
// wave per node; 4 edge-slots x 16 lanes; each lane gathers uint4 (8 bf16
// cols). Unroll 2 -> 8 edge-gathers in flight. Combine via shfl_xor(16,32).
// acc = sum_{s in N(t)} g[s] + g[t];  OUT==0: write bf16(dis*acc + b)
//                                     OUT==1: write f32 lrelu(dis*acc + b)
template <int OUT>
__global__ __launch_bounds__(512) void agg_kernel(
    const unsigned short* __restrict__ g, const unsigned short* __restrict__ srcs,
    const int* __restrict__ off, const int* __restrict__ cnt,
    const float* __restrict__ dis, const float* __restrict__ bias,
    void* __restrict__ outv, int n) {
  int wid = (blockIdx.x * blockDim.x + threadIdx.x) >> 6;
  int lane = threadIdx.x & 63;
  if (wid >= n) return;
  int slot = lane >> 4;   // 0..3
  int cp = lane & 15;     // uint4 index: cols 8cp..8cp+7

  float a0 = 0.f, a1 = 0.f, a2 = 0.f, a3 = 0.f;
  float a4 = 0.f, a5 = 0.f, a6 = 0.f, a7 = 0.f;

#define ACC_U4(U)                                \
  do {                                           \
    a0 += __uint_as_float((U).x << 16);          \
    a1 += __uint_as_float((U).x & 0xFFFF0000u);  \
    a2 += __uint_as_float((U).y << 16);          \
    a3 += __uint_as_float((U).y & 0xFFFF0000u);  \
    a4 += __uint_as_float((U).z << 16);          \
    a5 += __uint_as_float((U).z & 0xFFFF0000u);  \
    a6 += __uint_as_float((U).w << 16);          \
    a7 += __uint_as_float((U).w & 0xFFFF0000u);  \
  } while (0)

  if (slot == 0) {  // self term g[wid] (added once)
    uint4 sv = ((const uint4*)(g + (size_t)wid * DF))[cp];
    ACC_U4(sv);
  }

  int s = off[wid];
  int e = s + cnt[wid];
  int jb = s;
  int m8 = s + (((e - s) >> 3) << 3);
  for (; jb < m8; jb += 8) {  // 2 x 4 slots
    int s0 = (int)srcs[jb + slot];
    int s1 = (int)srcs[jb + 4 + slot];
    uint4 u0 = ((const uint4*)(g + (size_t)s0 * DF))[cp];
    uint4 u1 = ((const uint4*)(g + (size_t)s1 * DF))[cp];
    ACC_U4(u0);
    ACC_U4(u1);
  }
  for (; jb + 4 <= e; jb += 4) {  // 1 x 4 slots
    int s0 = (int)srcs[jb + slot];
    uint4 u0 = ((const uint4*)(g + (size_t)s0 * DF))[cp];
    ACC_U4(u0);
  }
  int rem = e - jb;  // 0..3
  if (slot < rem) {
    int s0 = (int)srcs[jb + slot];
    uint4 u0 = ((const uint4*)(g + (size_t)s0 * DF))[cp];
    ACC_U4(u0);
  }
#undef ACC_U4

  // combine the four slots (lanes L, L^16, L^32, L^48 hold same cols)
  a0 += __shfl_xor(a0, 16, 64); a1 += __shfl_xor(a1, 16, 64);
  a2 += __shfl_xor(a2, 16, 64); a3 += __shfl_xor(a3, 16, 64);
  a4 += __shfl_xor(a4, 16, 64); a5 += __shfl_xor(a5, 16, 64);
  a6 += __shfl_xor(a6, 16, 64); a7 += __shfl_xor(a7, 16, 64);
  a0 += __shfl_xor(a0, 32, 64); a1 += __shfl_xor(a1, 32, 64);
  a2 += __shfl_xor(a2, 32, 64); a3 += __shfl_xor(a3, 32, 64);
  a4 += __shfl_xor(a4, 32, 64); a5 += __shfl_xor(a5, 32, 64);
  a6 += __shfl_xor(a6, 32, 64); a7 += __shfl_xor(a7, 32, 64);

  if (slot == 0) {
    float diw = dis[wid];
    float4 b0 = ((const float4*)bias)[2 * cp];
    float4 b1 = ((const float4*)bias)[2 * cp + 1];
    a0 = fmaf(a0, diw, b0.x);
    a1 = fmaf(a1, diw, b0.y);
    a2 = fmaf(a2, diw, b0.z);
    a3 = fmaf(a3, diw, b0.w);
    a4 = fmaf(a4, diw, b1.x);
    a5 = fmaf(a5, diw, b1.y);
    a6 = fmaf(a6, diw, b1.z);
    a7 = fmaf(a7, diw, b1.w);
    if (OUT == 0) {
      uint4 p;
      p.x = (unsigned int)f2bf(a0) | ((unsigned int)f2bf(a1) << 16);
      p.y = (unsigned int)f2bf(a2) | ((unsigned int)f2bf(a3) << 16);
      p.z = (unsigned int)f2bf(a4) | ((unsigned int)f2bf(a5) << 16);
      p.w = (unsigned int)f2bf(a6) | ((unsigned int)f2bf(a7) << 16);
      ((uint4*)((unsigned short*)outv + (size_t)wid * DF))[cp] = p;
    } else {
      float4 r0, r1;
      r0.x = lrelu(a0); r0.y = lrelu(a1); r0.z = lrelu(a2); r0.w = lrelu(a3);
      r1.x = lrelu(a4); r1.y = lrelu(a5); r1.z = lrelu(a6); r1.w = lrelu(a7);
      ((float4*)((float*)outv + (size_t)wid * DF))[2 * cp] = r0;
      ((float4*)((float*)outv + (size_t)wid * DF))[2 * cp + 1] = r1;
    }
  }
}

// ---------------------------------------------------------------- launch
extern "C" void kernel_launch(void* const* d_in, const int* in_sizes, int n_in,
                              void* d_out, int out_size, void* d_ws, size_t ws_size,
                              hipStream_t stream) {
  const float* x  = (const float*)d_in[0];
  const void*  ei = d_in[1];
  const float* W1 = (const float*)d_in[2];
  const float* b1 = (const float*)d_in[3];
  const float* W2 = (const float*)d_in[4];
  const float* b2 = (const float*)d_in[5];
  float* out = (float*)d_out;

  int n = in_sizes[0] / DF;  // 50000
  int E = in_sizes[1] / 2;   // 800000
  int NBUCK = (n + 255) >> 8;              // 196
  int NCHUNK = (E + CHUNK - 1) / CHUNK;    // 391

  // workspace carve (16B aligned)
  char* w = (char*)d_ws;
  auto carve = [&](size_t bytes) {
    char* p = w;
    w += (bytes + 15) & ~(size_t)15;
    return p;
  };
  float* dis    = (float*)carve((size_t)n * 4);
  int*   cnt    = (int*)carve((size_t)n * 4);
  int*   off    = (int*)carve((size_t)n * 4);
  int*   flag   = (int*)carve(16);
  int*   btot   = (int*)carve((size_t)NBUCK * 4);
  int*   M      = (int*)carve((size_t)NBUCK * NCHUNK * 4);
  unsigned short* wfrag = (unsigned short*)carve(131072);  // 2 x (hi+lo)
  unsigned int* pairs   = (unsigned int*)carve((size_t)E * 4);
  unsigned int* staging = (unsigned int*)carve((size_t)E * 4);
  unsigned short* srcs  = (unsigned short*)carve((size_t)E * 2);
  unsigned short* bufG  = (unsigned short*)carve((size_t)n * DF * 2);
  unsigned short* bufH  = (unsigned short*)carve((size_t)n * DF * 2);

  // CSR build: exact counting sort by bucket = target>>8 (no global atomics)
  prep_kernel<<<3, 256, 0, stream>>>(W1, W2, wfrag, (const unsigned int*)ei, E, flag);
  p1a_kernel<<<NCHUNK, 256, 0, stream>>>(ei, E, flag, M, pairs, NBUCK, NCHUNK);
  matscanA_kernel<<<NBUCK, 256, 0, stream>>>(M, btot, NCHUNK);
  p1c_kernel<<<NCHUNK, 256, 0, stream>>>(pairs, E, M, btot, NBUCK, NCHUNK,
                                         staging);
  p2_kernel<<<NBUCK, 256, 0, stream>>>(staging, btot, NBUCK, off, cnt, dis,
                                       srcs, n);

  int gGemm = (n + 31) / 32;        // 1563
  int gAgg  = (n + 7) / 8;          // 6250 (8 waves/block)

  // layer 1: g1 = dis * bf16(x @ W1) ; h1 = bf16(dis*(sum g1 + g1_self) + b1)
  gemm_f32_kernel<<<gGemm, 256, 0, stream>>>(x, wfrag, dis, bufG, n);
  agg_kernel<0><<<gAgg, 512, 0, stream>>>(bufG, srcs, off, cnt, dis, b1, bufH, n);

  // layer 2: g2 = dis * bf16(h1 @ W2) ; out = lrelu(dis*(sum g2 + g2_self) + b2)
  gemm_bf16_kernel<<<gGemm, 256, 0, stream>>>(bufH, wfrag + 32768, dis, bufG, n);
  agg_kernel<1><<<gAgg, 512, 0, stream>>>(bufG, srcs, off, cnt, dis, b2, out, n);
}

// Round 13
// 164.911 us; speedup vs baseline: 4.6356x; 1.0067x over previous
//
#include <hip/hip_runtime.h>

#define DF 128      // feature dim
#define CHUNK 2048  // edges per chunk in counting sort
#define LSTCAP 6144 // LDS staging cap in p2 (bucket avg ~4096 + slack)

typedef __bf16 bf16x8 __attribute__((ext_vector_type(8)));
typedef float f32x4 __attribute__((ext_vector_type(4)));

// NOTE: packing assumes n <= 65536, NBUCK <= 256, NCHUNK <= 512
// (problem fixes n = 50000, E = 800000 -> NBUCK = 196, NCHUNK = 391).

// ---------------------------------------------------------------- utilities
static __device__ __forceinline__ float lrelu(float x) {
  return x > 0.f ? x : 0.1f * x;
}
static __device__ __forceinline__ unsigned short f2bf(float f) {
  unsigned int u = __float_as_uint(f);
  u += 0x7FFFu + ((u >> 16) & 1u);
  return (unsigned short)(u >> 16);
}
static __device__ __forceinline__ float bf2f(unsigned short h) {
  return __uint_as_float((unsigned int)h << 16);
}

// ---------------------------------------------------------------- wsplit:
// split W1/W2 into bf16 hi/lo in MFMA B-fragment-linear order.
__global__ void wsplit_kernel(const float* __restrict__ W1,
                              const float* __restrict__ W2,
                              unsigned short* __restrict__ wfrag) {
  const float* W = (blockIdx.x == 0) ? W1 : W2;
  unsigned short* hi = wfrag + (size_t)blockIdx.x * 32768;
  unsigned short* lo = hi + 16384;
  for (int i = threadIdx.x; i < 16384; i += 256) {
    int k = i >> 7, c = i & 127;
    float w = W[i];
    unsigned short h = f2bf(w);
    unsigned short l = f2bf(w - bf2f(h));
    int fid = (((k >> 5) * 8) + (c >> 4)) * 64 + ((k >> 3) & 3) * 16 + (c & 15);
    int pos = fid * 8 + (k & 7);
    hi[pos] = h;
    lo[pos] = l;
  }
}

// ---------------------------------------------------------------- pass 1a:
// per-chunk bucket histogram (bucket = target >> 8) + pack pairs.
// int64-vs-int32 detected block-locally (256 odd-word samples; an int32
// buffer of node ids < 65536 has all-zero odd words with prob ~(1/n)^256).
// M stored TRANSPOSED: M[bucket * NCHUNK + chunk].
__global__ __launch_bounds__(256) void p1a_kernel(
    const void* __restrict__ ei, int E, int* __restrict__ M,
    unsigned int* __restrict__ pairs, int NBUCK, int NCHUNK) {
  __shared__ int h[256];
  __shared__ int any32;
  int tid = threadIdx.x;
  if (tid == 0) any32 = 0;
  h[tid] = 0;
  __syncthreads();
  int base = blockIdx.x * CHUNK;
  int end = min(base + CHUNK, E);
  {
    const unsigned int* u = (const unsigned int*)ei;
    long long i = (long long)base + tid * 8;
    if (i < end && u[2 * i + 1] != 0u) any32 = 1;
  }
  __syncthreads();
  int is64 = !any32;
  if (is64) {
    const long long* p = (const long long*)ei;
    for (int i = base + tid; i < end; i += 256) {
      int src = (int)p[i];
      int c = (int)p[(size_t)E + i];
      atomicAdd(&h[c >> 8], 1);
      pairs[i] = ((unsigned)src << 16) | (unsigned)c;
    }
  } else {
    const int* p = (const int*)ei;
    for (int i = base + tid; i < end; i += 256) {
      int src = p[i];
      int c = p[(size_t)E + i];
      atomicAdd(&h[c >> 8], 1);
      pairs[i] = ((unsigned)src << 16) | (unsigned)c;
    }
  }
  __syncthreads();
  if (tid < NBUCK) M[tid * NCHUNK + blockIdx.x] = h[tid];
}

// ---------------------------------------------------------------- matscanA:
// one block per bucket: exclusive scan of that bucket's chunk row (2 per
// thread), write row total into btot.
__global__ __launch_bounds__(256) void matscanA_kernel(int* __restrict__ M,
                                                       int* __restrict__ btot,
                                                       int NCHUNK) {
  __shared__ int s[256];
  int tid = threadIdx.x;
  int base = blockIdx.x * NCHUNK;
  int i0 = tid * 2, i1 = tid * 2 + 1;
  int v0 = (i0 < NCHUNK) ? M[base + i0] : 0;
  int v1 = (i1 < NCHUNK) ? M[base + i1] : 0;
  int loc = v0 + v1;
  s[tid] = loc;
  __syncthreads();
  for (int d = 1; d < 256; d <<= 1) {
    int add = (tid >= d) ? s[tid - d] : 0;
    __syncthreads();
    s[tid] += add;
    __syncthreads();
  }
  int excl = s[tid] - loc;
  if (i0 < NCHUNK) M[base + i0] = excl;
  if (i1 < NCHUNK) M[base + i1] = excl + v0;
  if (tid == 255) btot[blockIdx.x] = s[255];
}

// ---------------------------------------------------------------- pass 1c:
// scatter pairs into exact per-(chunk,bucket) staging slots. bstart computed
// in-block by scanning btot (196 values). Ranks via LDS atomics.
__global__ __launch_bounds__(256) void p1c_kernel(
    const unsigned int* __restrict__ pairs, int E, const int* __restrict__ M,
    const int* __restrict__ btot, int NBUCK, int NCHUNK,
    unsigned int* __restrict__ staging) {
  __shared__ int bs[256];
  __shared__ int rowM[256];
  __shared__ int lcur[256];
  int tid = threadIdx.x;
  int blk = blockIdx.x;
  int v = (tid < NBUCK) ? btot[tid] : 0;
  bs[tid] = v;
  __syncthreads();
  for (int d = 1; d < 256; d <<= 1) {
    int add = (tid >= d) ? bs[tid - d] : 0;
    __syncthreads();
    bs[tid] += add;
    __syncthreads();
  }
  if (tid < NBUCK) rowM[tid] = M[tid * NCHUNK + blk] + (bs[tid] - v);
  lcur[tid] = 0;
  __syncthreads();
  int base = blk * CHUNK;
  int end = min(base + CHUNK, E);
  for (int i = base + tid; i < end; i += 256) {
    unsigned pv = pairs[i];
    int b = (int)((pv & 0xFFFFu) >> 8);
    int r = atomicAdd(&lcur[b], 1);
    staging[rowM[b] + r] = pv;
  }
}

// ---------------------------------------------------------------- pass 2:
// one block per bucket: LDS histogram + scan of the 256 nodes, emit
// offcnt/dis densely, scatter srcs (ushort) into the bucket's CSR window.
__global__ __launch_bounds__(256) void p2_kernel(
    const unsigned int* __restrict__ staging, const int* __restrict__ btot,
    int NBUCK, int2* __restrict__ offcnt, float* __restrict__ dis,
    unsigned short* __restrict__ srcs, int n) {
  __shared__ int bs[256], h[256], ex[256], lcur[256];
  __shared__ unsigned int lst[LSTCAP];
  int tid = threadIdx.x;
  int b = blockIdx.x;
  int v = (tid < NBUCK) ? btot[tid] : 0;
  bs[tid] = v;
  h[tid] = 0;
  lcur[tid] = 0;
  __syncthreads();
  for (int d = 1; d < 256; d <<= 1) {
    int add = (tid >= d) ? bs[tid - d] : 0;
    __syncthreads();
    bs[tid] += add;
    __syncthreads();
  }
  int lenb = btot[b];
  int base = bs[b] - lenb;  // exclusive prefix at b
  __syncthreads();
  for (int i = tid; i < lenb; i += 256) {
    unsigned int pv = staging[base + i];
    if (i < LSTCAP) lst[i] = pv;
    atomicAdd(&h[pv & 255u], 1);
  }
  __syncthreads();
  int my = h[tid];
  ex[tid] = my;
  __syncthreads();
  for (int d = 1; d < 256; d <<= 1) {
    int add = (tid >= d) ? ex[tid - d] : 0;
    __syncthreads();
    ex[tid] += add;
    __syncthreads();
  }
  int excl = ex[tid] - my;
  ex[tid] = excl;
  int node = (b << 8) + tid;
  if (node < n) {
    offcnt[node] = make_int2(base + excl, my);
    dis[node] = rsqrtf((float)(my + 1));  // deg incl self loop >= 1
  }
  __syncthreads();
  for (int i = tid; i < lenb; i += 256) {
    unsigned int pv = (i < LSTCAP) ? lst[i] : staging[base + i];
    int ci = (int)(pv & 255u);
    int r = atomicAdd(&lcur[ci], 1);
    srcs[base + ex[ci] + r] = (unsigned short)(pv >> 16);
  }
}

// ---------------------------------------------------------------- MFMA GEMM, fp32 A (split hi/lo, 3 MFMA)
// G_bf16[n x 128] = dis[row] * (A_f32[n x 128] @ W[128 x 128])
// Epilogue: stage C tile in LDS (stride 136), store coalesced uint4.
__global__ __launch_bounds__(256, 8) void gemm_f32_kernel(
    const float* __restrict__ A, const unsigned short* __restrict__ wfrag,
    const float* __restrict__ dis, unsigned short* __restrict__ G, int n) {
  __shared__ unsigned short Ah[2][4][64][8];
  __shared__ unsigned short Al[2][4][64][8];
  __shared__ unsigned short Cs[32 * 136];
  __shared__ float disS[32];
  int tid = threadIdx.x;
  int row0 = blockIdx.x * 32;

  if (tid < 32) {
    int gr = row0 + tid;
    disS[tid] = (gr < n) ? dis[gr] : 0.f;
  }

  const float4* A4 = (const float4*)A;
#pragma unroll
  for (int it = 0; it < 4; ++it) {
    int fi = it * 256 + tid;
    int row = fi >> 5;          // 0..31
    int c4 = fi & 31;           // float4 index along k
    int gr = row0 + row;
    float4 v = make_float4(0.f, 0.f, 0.f, 0.f);
    if (gr < n) v = A4[(size_t)gr * 32 + c4];
    unsigned short h0 = f2bf(v.x), h1 = f2bf(v.y), h2 = f2bf(v.z), h3 = f2bf(v.w);
    unsigned short l0 = f2bf(v.x - bf2f(h0)), l1 = f2bf(v.y - bf2f(h1));
    unsigned short l2 = f2bf(v.z - bf2f(h2)), l3 = f2bf(v.w - bf2f(h3));
    int band = row >> 4;
    int kslab = c4 >> 3;
    int lane = ((c4 >> 1) & 3) * 16 + (row & 15);
    int e0 = (c4 & 1) * 4;
    *(uint2*)&Ah[band][kslab][lane][e0] =
        make_uint2((unsigned int)h0 | ((unsigned int)h1 << 16),
                   (unsigned int)h2 | ((unsigned int)h3 << 16));
    *(uint2*)&Al[band][kslab][lane][e0] =
        make_uint2((unsigned int)l0 | ((unsigned int)l1 << 16),
                   (unsigned int)l2 | ((unsigned int)l3 << 16));
  }
  __syncthreads();

  int w = tid >> 6, lane = tid & 63;
  int band = w & 1, ch = w >> 1;

  f32x4 acc[4];
#pragma unroll
  for (int t = 0; t < 4; ++t) acc[t] = (f32x4){0.f, 0.f, 0.f, 0.f};

#pragma unroll
  for (int ks = 0; ks < 4; ++ks) {
    bf16x8 ahi = *(const bf16x8*)&Ah[band][ks][lane][0];
    bf16x8 alo = *(const bf16x8*)&Al[band][ks][lane][0];
#pragma unroll
    for (int ct = 0; ct < 4; ++ct) {
      size_t fb = ((size_t)(ks * 8 + ch * 4 + ct) * 64 + lane) * 8;
      bf16x8 whi = *(const bf16x8*)&wfrag[fb];
      bf16x8 wlo = *(const bf16x8*)&wfrag[16384 + fb];
      acc[ct] = __builtin_amdgcn_mfma_f32_16x16x32_bf16(ahi, whi, acc[ct], 0, 0, 0);
      acc[ct] = __builtin_amdgcn_mfma_f32_16x16x32_bf16(ahi, wlo, acc[ct], 0, 0, 0);
      acc[ct] = __builtin_amdgcn_mfma_f32_16x16x32_bf16(alo, whi, acc[ct], 0, 0, 0);
    }
  }

#pragma unroll
  for (int ct = 0; ct < 4; ++ct) {
    int col = ch * 64 + ct * 16 + (lane & 15);
#pragma unroll
    for (int r = 0; r < 4; ++r) {
      int lrow = band * 16 + ((lane >> 4) << 2) + r;
      Cs[lrow * 136 + col] = f2bf(acc[ct][r] * disS[lrow]);
    }
  }
  __syncthreads();
#pragma unroll
  for (int it = 0; it < 2; ++it) {
    int fi = it * 256 + tid;   // 0..511 = 32 rows x 16 uint4
    int row = fi >> 4, q = fi & 15;
    int gr = row0 + row;
    if (gr < n)
      ((uint4*)(G + (size_t)gr * DF))[q] = *(uint4*)&Cs[row * 136 + q * 8];
  }
}

// ---------------------------------------------------------------- MFMA GEMM, bf16 A (2 MFMA)
__global__ __launch_bounds__(256, 8) void gemm_bf16_kernel(
    const unsigned short* __restrict__ A, const unsigned short* __restrict__ wfrag,
    const float* __restrict__ dis, unsigned short* __restrict__ G, int n) {
  __shared__ unsigned short Ah[2][4][64][8];
  __shared__ unsigned short Cs[32 * 136];
  __shared__ float disS[32];
  int tid = threadIdx.x;
  int row0 = blockIdx.x * 32;

  if (tid < 32) {
    int gr = row0 + tid;
    disS[tid] = (gr < n) ? dis[gr] : 0.f;
  }

  const uint4* A4 = (const uint4*)A;  // 8 bf16 per uint4
#pragma unroll
  for (int it = 0; it < 2; ++it) {
    int fi = it * 256 + tid;    // 0..511
    int row = fi >> 4;          // 0..31
    int m = fi & 15;            // 8-k group
    int gr = row0 + row;
    uint4 v = make_uint4(0u, 0u, 0u, 0u);
    if (gr < n) v = A4[(size_t)gr * 16 + m];
    int band = row >> 4;
    int kslab = m >> 2;
    int lane = (m & 3) * 16 + (row & 15);
    *(uint4*)&Ah[band][kslab][lane][0] = v;
  }
  __syncthreads();

  int w = tid >> 6, lane = tid & 63;
  int band = w & 1, ch = w >> 1;

  f32x4 acc[4];
#pragma unroll
  for (int t = 0; t < 4; ++t) acc[t] = (f32x4){0.f, 0.f, 0.f, 0.f};

#pragma unroll
  for (int ks = 0; ks < 4; ++ks) {
    bf16x8 ahi = *(const bf16x8*)&Ah[band][ks][lane][0];
#pragma unroll
    for (int ct = 0; ct < 4; ++ct) {
      size_t fb = ((size_t)(ks * 8 + ch * 4 + ct) * 64 + lane) * 8;
      bf16x8 whi = *(const bf16x8*)&wfrag[fb];
      bf16x8 wlo = *(const bf16x8*)&wfrag[16384 + fb];
      acc[ct] = __builtin_amdgcn_mfma_f32_16x16x32_bf16(ahi, whi, acc[ct], 0, 0, 0);
      acc[ct] = __builtin_amdgcn_mfma_f32_16x16x32_bf16(ahi, wlo, acc[ct], 0, 0, 0);
    }
  }

#pragma unroll
  for (int ct = 0; ct < 4; ++ct) {
    int col = ch * 64 + ct * 16 + (lane & 15);
#pragma unroll
    for (int r = 0; r < 4; ++r) {
      int lrow = band * 16 + ((lane >> 4) << 2) + r;
      Cs[lrow * 136 + col] = f2bf(acc[ct][r] * disS[lrow]);
    }
  }
  __syncthreads();
#pragma unroll
  for (int it = 0; it < 2; ++it) {
    int fi = it * 256 + tid;
    int row = fi >> 4, q = fi & 15;
    int gr = row0 + row;
    if (gr < n)
      ((uint4*)(G + (size_t)gr * DF))[q] = *(uint4*)&Cs[row * 136 + q * 8];
  }
}

// ---------------------------------------------------------------- aggregation
// wave per node; 4 edge-slots x 16 lanes; each lane gathers uint4 (8 bf16
// cols). Unroll 4 -> 16 edge-gathers (4 KB) in flight per wave. Combine via
// shfl_xor(16,32).
// acc = sum_{s in N(t)} g[s] + g[t];  OUT==0: write bf16(dis*acc + b)
//                                     OUT==1: write f32 lrelu(dis*acc + b)
template <int OUT>
__global__ __launch_bounds__(512) void agg_kernel(
    const unsigned short* __restrict__ g, const unsigned short* __restrict__ srcs,
    const int2* __restrict__ offcnt, const float* __restrict__ dis,
    const float* __restrict__ bias, void* __restrict__ outv, int n) {
  int wid = (blockIdx.x * blockDim.x + threadIdx.x) >> 6;
  int lane = threadIdx.x & 63;
  if (wid >= n) return;
  int slot = lane >> 4;   // 0..3
  int cp = lane & 15;     // uint4 index: cols 8cp..8cp+7

  float a0 = 0.f, a1 = 0.f, a2 = 0.f, a3 = 0.f;
  float a4 = 0.f, a5 = 0.f, a6 = 0.f, a7 = 0.f;

#define ACC_U4(U)                                \
  do {                                           \
    a0 += __uint_as_float((U).x << 16);          \
    a1 += __uint_as_float((U).x & 0xFFFF0000u);  \
    a2 += __uint_as_float((U).y << 16);          \
    a3 += __uint_as_float((U).y & 0xFFFF0000u);  \
    a4 += __uint_as_float((U).z << 16);          \
    a5 += __uint_as_float((U).z & 0xFFFF0000u);  \
    a6 += __uint_as_float((U).w << 16);          \
    a7 += __uint_as_float((U).w & 0xFFFF0000u);  \
  } while (0)

  if (slot == 0) {  // self term g[wid] (added once)
    uint4 sv = ((const uint4*)(g + (size_t)wid * DF))[cp];
    ACC_U4(sv);
  }

  int2 oc = offcnt[wid];
  int s = oc.x;
  int e = s + oc.y;
  int jb = s;
  int m16 = s + (((e - s) >> 4) << 4);
  for (; jb < m16; jb += 16) {  // 4 loads in flight x 4 slots
    int s0 = (int)srcs[jb + slot];
    int s1 = (int)srcs[jb + 4 + slot];
    int s2 = (int)srcs[jb + 8 + slot];
    int s3 = (int)srcs[jb + 12 + slot];
    uint4 u0 = ((const uint4*)(g + (size_t)s0 * DF))[cp];
    uint4 u1 = ((const uint4*)(g + (size_t)s1 * DF))[cp];
    uint4 u2 = ((const uint4*)(g + (size_t)s2 * DF))[cp];
    uint4 u3 = ((const uint4*)(g + (size_t)s3 * DF))[cp];
    ACC_U4(u0);
    ACC_U4(u1);
    ACC_U4(u2);
    ACC_U4(u3);
  }
  if (jb + 8 <= e) {  // 2 x 4 slots
    int s0 = (int)srcs[jb + slot];
    int s1 = (int)srcs[jb + 4 + slot];
    uint4 u0 = ((const uint4*)(g + (size_t)s0 * DF))[cp];
    uint4 u1 = ((const uint4*)(g + (size_t)s1 * DF))[cp];
    ACC_U4(u0);
    ACC_U4(u1);
    jb += 8;
  }
  if (jb + 4 <= e) {  // 1 x 4 slots
    int s0 = (int)srcs[jb + slot];
    uint4 u0 = ((const uint4*)(g + (size_t)s0 * DF))[cp];
    ACC_U4(u0);
    jb += 4;
  }
  int rem = e - jb;  // 0..3
  if (slot < rem) {
    int s0 = (int)srcs[jb + slot];
    uint4 u0 = ((const uint4*)(g + (size_t)s0 * DF))[cp];
    ACC_U4(u0);
  }
#undef ACC_U4

  // combine the four slots (lanes L, L^16, L^32, L^48 hold same cols)
  a0 += __shfl_xor(a0, 16, 64); a1 += __shfl_xor(a1, 16, 64);
  a2 += __shfl_xor(a2, 16, 64); a3 += __shfl_xor(a3, 16, 64);
  a4 += __shfl_xor(a4, 16, 64); a5 += __shfl_xor(a5, 16, 64);
  a6 += __shfl_xor(a6, 16, 64); a7 += __shfl_xor(a7, 16, 64);
  a0 += __shfl_xor(a0, 32, 64); a1 += __shfl_xor(a1, 32, 64);
  a2 += __shfl_xor(a2, 32, 64); a3 += __shfl_xor(a3, 32, 64);
  a4 += __shfl_xor(a4, 32, 64); a5 += __shfl_xor(a5, 32, 64);
  a6 += __shfl_xor(a6, 32, 64); a7 += __shfl_xor(a7, 32, 64);

  if (slot == 0) {
    float diw = dis[wid];
    float4 b0 = ((const float4*)bias)[2 * cp];
    float4 b1 = ((const float4*)bias)[2 * cp + 1];
    a0 = fmaf(a0, diw, b0.x);
    a1 = fmaf(a1, diw, b0.y);
    a2 = fmaf(a2, diw, b0.z);
    a3 = fmaf(a3, diw, b0.w);
    a4 = fmaf(a4, diw, b1.x);
    a5 = fmaf(a5, diw, b1.y);
    a6 = fmaf(a6, diw, b1.z);
    a7 = fmaf(a7, diw, b1.w);
    if (OUT == 0) {
      uint4 p;
      p.x = (unsigned int)f2bf(a0) | ((unsigned int)f2bf(a1) << 16);
      p.y = (unsigned int)f2bf(a2) | ((unsigned int)f2bf(a3) << 16);
      p.z = (unsigned int)f2bf(a4) | ((unsigned int)f2bf(a5) << 16);
      p.w = (unsigned int)f2bf(a6) | ((unsigned int)f2bf(a7) << 16);
      ((uint4*)((unsigned short*)outv + (size_t)wid * DF))[cp] = p;
    } else {
      float4 r0, r1;
      r0.x = lrelu(a0); r0.y = lrelu(a1); r0.z = lrelu(a2); r0.w = lrelu(a3);
      r1.x = lrelu(a4); r1.y = lrelu(a5); r1.z = lrelu(a6); r1.w = lrelu(a7);
      ((float4*)((float*)outv + (size_t)wid * DF))[2 * cp] = r0;
      ((float4*)((float*)outv + (size_t)wid * DF))[2 * cp + 1] = r1;
    }
  }
}

// ---------------------------------------------------------------- launch
extern "C" void kernel_launch(void* const* d_in, const int* in_sizes, int n_in,
                              void* d_out, int out_size, void* d_ws, size_t ws_size,
                              hipStream_t stream) {
  const float* x  = (const float*)d_in[0];
  const void*  ei = d_in[1];
  const float* W1 = (const float*)d_in[2];
  const float* b1 = (const float*)d_in[3];
  const float* W2 = (const float*)d_in[4];
  const float* b2 = (const float*)d_in[5];
  float* out = (float*)d_out;

  int n = in_sizes[0] / DF;  // 50000
  int E = in_sizes[1] / 2;   // 800000
  int NBUCK = (n + 255) >> 8;              // 196
  int NCHUNK = (E + CHUNK - 1) / CHUNK;    // 391

  // workspace carve (16B aligned)
  char* w = (char*)d_ws;
  auto carve = [&](size_t bytes) {
    char* p = w;
    w += (bytes + 15) & ~(size_t)15;
    return p;
  };
  float* dis    = (float*)carve((size_t)n * 4);
  int2*  offcnt = (int2*)carve((size_t)n * 8);
  int*   btot   = (int*)carve((size_t)NBUCK * 4);
  int*   M      = (int*)carve((size_t)NBUCK * NCHUNK * 4);
  unsigned short* wfrag = (unsigned short*)carve(131072);  // 2 x (hi+lo)
  unsigned int* pairs   = (unsigned int*)carve((size_t)E * 4);
  unsigned int* staging = (unsigned int*)carve((size_t)E * 4);
  unsigned short* srcs  = (unsigned short*)carve((size_t)E * 2);
  unsigned short* bufG  = (unsigned short*)carve((size_t)n * DF * 2);
  unsigned short* bufH  = (unsigned short*)carve((size_t)n * DF * 2);

  // CSR build: exact counting sort by bucket = target>>8 (no global atomics)
  wsplit_kernel<<<2, 256, 0, stream>>>(W1, W2, wfrag);
  p1a_kernel<<<NCHUNK, 256, 0, stream>>>(ei, E, M, pairs, NBUCK, NCHUNK);
  matscanA_kernel<<<NBUCK, 256, 0, stream>>>(M, btot, NCHUNK);
  p1c_kernel<<<NCHUNK, 256, 0, stream>>>(pairs, E, M, btot, NBUCK, NCHUNK,
                                         staging);
  p2_kernel<<<NBUCK, 256, 0, stream>>>(staging, btot, NBUCK, offcnt, dis,
                                       srcs, n);

  int gGemm = (n + 31) / 32;        // 1563
  int gAgg  = (n + 7) / 8;          // 6250 (8 waves/block)

  // layer 1: g1 = dis * bf16(x @ W1) ; h1 = bf16(dis*(sum g1 + g1_self) + b1)
  gemm_f32_kernel<<<gGemm, 256, 0, stream>>>(x, wfrag, dis, bufG, n);
  agg_kernel<0><<<gAgg, 512, 0, stream>>>(bufG, srcs, offcnt, dis, b1, bufH, n);

  // layer 2: g2 = dis * bf16(h1 @ W2) ; out = lrelu(dis*(sum g2 + g2_self) + b2)
  gemm_bf16_kernel<<<gGemm, 256, 0, stream>>>(bufH, wfrag + 32768, dis, bufG, n);
  agg_kernel<1><<<gAgg, 512, 0, stream>>>(bufG, srcs, offcnt, dis, b2, out, n);
}